// Round 13
// baseline (10257.041 us; speedup 1.0000x reference)
//
#include <hip/hip_runtime.h>

#define T_DIM 512
#define B_DIM 64
#define H_DIM 1024
#define NKS 32                 // MFMA K-steps (K=32 each)

typedef __attribute__((ext_vector_type(8))) short bf16x8;
typedef __attribute__((ext_vector_type(4))) float f32x4;

// ws layout:
//   Wpk  [6][64 jt][32 ks][64 lane][8 e] bf16   weights in B-fragment order, tril-masked
//   hbuf [2][B][H] f32                          hidden ping-pong (agent-scope coherent)
//   pmax [T][B][32] f32                         per-pair label maxes
//   barc [8][64] u32                            per-bgroup monotone barrier counters

__device__ __forceinline__ unsigned short f2bf(float f) {
    unsigned u = __float_as_uint(f);
    unsigned r = (u + 0x7FFFu + ((u >> 16) & 1u)) >> 16;   // RNE
    return (unsigned short)r;
}

// ---------------- prep: pack weights into MFMA B-fragment order ----------------
// elem index = (((g*64 + jt)*32 + ks)*64 + lane)*8 + e
// content: B[k][j] = (k>=j ? W_g[k][j] : 0), j = jt*16 + (lane&15),
//          k = ks*32 + (lane>>4)*8 + e   (same k-map used for A-frags -> layout-agnostic)
__global__ __launch_bounds__(256) void prep_pack(
    const float* __restrict__ Wir, const float* __restrict__ Wiz, const float* __restrict__ Win,
    const float* __restrict__ Whr, const float* __restrict__ Whz, const float* __restrict__ Whn,
    unsigned short* __restrict__ Wpk)
{
    const float* srcs[6] = {Wir, Wiz, Win, Whr, Whz, Whn};
    const unsigned c = blockIdx.x * 256 + threadIdx.x;     // ushort4 chunk id, < 1572864
    const int e0   = (c & 1) * 4;
    const int lane = (c >> 1) & 63;
    const int ks   = (c >> 7) & 31;
    const int jt   = (c >> 12) & 63;
    const int g    = (int)(c >> 18);
    const float* src = srcs[g];
    const int j  = jt * 16 + (lane & 15);
    const int kb = ks * 32 + (lane >> 4) * 8 + e0;
    ushort4 o;
    unsigned short* po = (unsigned short*)&o;
    #pragma unroll
    for (int i = 0; i < 4; ++i) {
        const int k = kb + i;
        const float w = (k >= j) ? src[(size_t)k * H_DIM + j] : 0.0f;
        po[i] = f2bf(w);
    }
    *((ushort4*)Wpk + c) = o;
}

__global__ __launch_bounds__(256) void init_h(const float* __restrict__ h0,
                                              float* __restrict__ hbuf,
                                              unsigned* __restrict__ barc)
{
    if (blockIdx.x < 256) {
        const int i = blockIdx.x * 256 + threadIdx.x;
        if (i < B_DIM * H_DIM) hbuf[i] = h0[i];
    } else {
        #pragma unroll
        for (int k = 0; k < 2; ++k) barc[threadIdx.x + 256 * k] = 0u;
    }
}

// ---------------- main: 256 WGs x 1024 threads, MFMA core ----------------
// WG = (pair 0..31, bgroup 0..7 owning 8 b-rows). Tile A = 16 cols at 16*pair,
// tile B = 16 cols at 16*(63-pair). 16 waves: waves 0-7 tile A (4 K-steps each),
// waves 8-15 tile B. Per wave per step: 24 MFMA (6 gates x 4 ksteps).
__global__ __launch_bounds__(1024, 4) void gru_main(
    const float* __restrict__ x,      // [T,B,H]
    const unsigned short* __restrict__ Wpk,
    const float* __restrict__ bir, const float* __restrict__ bhr,
    const float* __restrict__ biz, const float* __restrict__ bhz,
    const float* __restrict__ bin_, const float* __restrict__ bhn,
    const float* __restrict__ Wout, const float* __restrict__ bout,
    float* __restrict__ hbuf,         // [2,B,H]
    float* __restrict__ pmax,         // [T,B,32]
    unsigned* __restrict__ barc)      // [8][64]
{
    // A-frag stores: elem = ((ks*4 + kg)*8 + row)*8 + e  (rows 0..7 only; rows 8..15 = zblk)
    __shared__ unsigned short axf[NKS * 4 * 8 * 8];   // x A-frags, 16 KB
    __shared__ unsigned short ahf[NKS * 4 * 8 * 8];   // h A-frags, 16 KB
    __shared__ unsigned short zblk[8];                // 16B zeros (broadcast source)
    __shared__ float red[16][6][64][4];               // per-wave acc tiles, 96 KB
    __shared__ float mxs[8][2];                       // [b][tile] label maxes

    const int tid  = threadIdx.x;
    const int lane = tid & 63;
    const int ww   = tid >> 6;        // 0..15
    const int row  = lane & 15;       // A row / D col-lane
    const int kg   = lane >> 4;       // k-group 0..3

    const int pair = blockIdx.x & 31;
    const int bg   = blockIdx.x >> 5; // 0..7 barrier group
    const int b0   = bg * 8;

    const int tile = ww >> 3;         // 0 = A, 1 = B
    const int wi   = ww & 7;          // k-slice within tile
    const int jt   = tile ? (63 - pair) : pair;
    const int ks0  = wi * 4;

    // epilogue constants (tid<256: tile = tid>>7, b = (tid>>4)&7, col = tid&15)
    const int ecol = tid & 15;
    const int eb   = (tid >> 4) & 7;
    const int ej   = ((tid >> 7) ? 16 * (63 - pair) : 16 * pair) + ecol;
    float c_bir = 0, c_bhr = 0, c_biz = 0, c_bhz = 0, c_bin = 0, c_bhn = 0, c_wo = 0, bo = 0;
    if (tid < 256) {
        c_bir = bir[ej]; c_bhr = bhr[ej]; c_biz = biz[ej]; c_bhz = bhz[ej];
        c_bin = bin_[ej]; c_bhn = bhn[ej]; c_wo = Wout[ej]; bo = bout[0];
    }

    // per-lane fragment pointers
    const unsigned short* pax0 = (row < 8) ? &axf[(kg * 8 + row) * 8] : zblk;
    const unsigned short* pah0 = (row < 8) ? &ahf[(kg * 8 + row) * 8] : zblk;
    const int astride = (row < 8) ? 256 : 0;          // elems per ks
    // weight base for (g=0, this jt, ks=0), + lane*8
    const unsigned short* pw0 = Wpk + ((size_t)jt * NKS) * 512 + lane * 8;
    const size_t GSTRIDE = (size_t)64 * NKS * 512;    // per-gate elems

    unsigned* mybar = barc + bg * 64;

    if (tid < 8) zblk[tid] = 0;
    __syncthreads();

    // ---- prologue: stage x(0) as bf16 A-frags ----
    {
        const float* xt0 = x;   // t = 0
        #pragma unroll
        for (int it = 0; it < 2; ++it) {
            const int fi = tid + it * 1024;           // 0..2047
            const int r  = fi >> 8;                   // b-row 0..7
            const int k  = (fi & 255) * 4;
            const float4 v = *(const float4*)(xt0 + (size_t)(b0 + r) * H_DIM + k);
            ushort4 o; unsigned short* po = (unsigned short*)&o;
            po[0] = f2bf(v.x); po[1] = f2bf(v.y); po[2] = f2bf(v.z); po[3] = f2bf(v.w);
            const int elem = (((k >> 5) * 4 + ((k >> 3) & 3)) * 8 + r) * 8 + (k & 7);
            *(ushort4*)&axf[elem] = o;
        }
    }

    for (int t = 0; t < T_DIM; ++t) {
        const float* hid  = hbuf + (size_t)(t & 1) * (B_DIM * H_DIM);
        float*       hidn = hbuf + (size_t)((t + 1) & 1) * (B_DIM * H_DIM);
        const float* xt   = x + (size_t)t * (B_DIM * H_DIM);

        // ---- wait: h(t) visible (32 arrivals per completed step); t=0 passes ----
        if (tid == 0) {
            const unsigned tgt = 32u * (unsigned)t;
            while (__hip_atomic_load(mybar, __ATOMIC_RELAXED, __HIP_MEMORY_SCOPE_AGENT) < tgt)
                __builtin_amdgcn_s_sleep(1);
        }
        __syncthreads();

        // ---- stage h(t) as bf16 A-frags (agent-scope reads) ----
        #pragma unroll
        for (int it = 0; it < 2; ++it) {
            const int fi = tid + it * 1024;
            const int r  = fi >> 8;
            const int k  = (fi & 255) * 4;
            const float* s4 = hid + (size_t)(b0 + r) * H_DIM + k;
            float4 v;
            v.x = __hip_atomic_load(s4 + 0, __ATOMIC_RELAXED, __HIP_MEMORY_SCOPE_AGENT);
            v.y = __hip_atomic_load(s4 + 1, __ATOMIC_RELAXED, __HIP_MEMORY_SCOPE_AGENT);
            v.z = __hip_atomic_load(s4 + 2, __ATOMIC_RELAXED, __HIP_MEMORY_SCOPE_AGENT);
            v.w = __hip_atomic_load(s4 + 3, __ATOMIC_RELAXED, __HIP_MEMORY_SCOPE_AGENT);
            ushort4 o; unsigned short* po = (unsigned short*)&o;
            po[0] = f2bf(v.x); po[1] = f2bf(v.y); po[2] = f2bf(v.z); po[3] = f2bf(v.w);
            const int elem = (((k >> 5) * 4 + ((k >> 3) & 3)) * 8 + r) * 8 + (k & 7);
            *(ushort4*)&ahf[elem] = o;
        }
        __syncthreads();

        // ---- MFMA phase: 4 ksteps x 6 gates, fp32 accumulate ----
        f32x4 acc0 = 0.0f, acc1 = 0.0f, acc2 = 0.0f;   // x-gates: ir, iz, in
        f32x4 acc3 = 0.0f, acc4 = 0.0f, acc5 = 0.0f;   // h-gates: hr, hz, hn
        #pragma unroll
        for (int q = 0; q < 4; ++q) {
            const int ks = ks0 + q;
            const bf16x8 ax = *(const bf16x8*)(pax0 + ks * astride);
            const bf16x8 ah = *(const bf16x8*)(pah0 + ks * astride);
            const unsigned short* pw = pw0 + (size_t)ks * 512;
            const bf16x8 w0 = *(const bf16x8*)(pw);
            const bf16x8 w1 = *(const bf16x8*)(pw + GSTRIDE);
            const bf16x8 w2 = *(const bf16x8*)(pw + 2 * GSTRIDE);
            const bf16x8 w3 = *(const bf16x8*)(pw + 3 * GSTRIDE);
            const bf16x8 w4 = *(const bf16x8*)(pw + 4 * GSTRIDE);
            const bf16x8 w5 = *(const bf16x8*)(pw + 5 * GSTRIDE);
            acc0 = __builtin_amdgcn_mfma_f32_16x16x32_bf16(ax, w0, acc0, 0, 0, 0);
            acc1 = __builtin_amdgcn_mfma_f32_16x16x32_bf16(ax, w1, acc1, 0, 0, 0);
            acc2 = __builtin_amdgcn_mfma_f32_16x16x32_bf16(ax, w2, acc2, 0, 0, 0);
            acc3 = __builtin_amdgcn_mfma_f32_16x16x32_bf16(ah, w3, acc3, 0, 0, 0);
            acc4 = __builtin_amdgcn_mfma_f32_16x16x32_bf16(ah, w4, acc4, 0, 0, 0);
            acc5 = __builtin_amdgcn_mfma_f32_16x16x32_bf16(ah, w5, acc5, 0, 0, 0);
        }

        // ---- write acc tiles to LDS ----
        *(f32x4*)&red[ww][0][lane][0] = acc0;
        *(f32x4*)&red[ww][1][lane][0] = acc1;
        *(f32x4*)&red[ww][2][lane][0] = acc2;
        *(f32x4*)&red[ww][3][lane][0] = acc3;
        *(f32x4*)&red[ww][4][lane][0] = acc4;
        *(f32x4*)&red[ww][5][lane][0] = acc5;
        __syncthreads();

        // ---- epilogue: 256 threads = (tile 2) x (b 8) x (col 16) ----
        if (tid < 256) {
            const int etile = tid >> 7;
            const int wbase = etile * 8;
            const int lp = ((eb >> 2) << 4) | ecol;   // D lane': row-group | col
            const int rr = eb & 3;                    // D reg index
            float s0 = 0, s1 = 0, s2 = 0, s3 = 0, s4 = 0, s5 = 0;
            #pragma unroll
            for (int wv = 0; wv < 8; ++wv) {
                s0 += red[wbase + wv][0][lp][rr];
                s1 += red[wbase + wv][1][lp][rr];
                s2 += red[wbase + wv][2][lp][rr];
                s3 += red[wbase + wv][3][lp][rr];
                s4 += red[wbase + wv][4][lp][rr];
                s5 += red[wbase + wv][5][lp][rr];
            }
            const float xv = xt[(size_t)(b0 + eb) * H_DIM + ej];
            const float hv = __hip_atomic_load(&hid[(size_t)(b0 + eb) * H_DIM + ej],
                                               __ATOMIC_RELAXED, __HIP_MEMORY_SCOPE_AGENT);
            const float rp = s0 + c_bir * xv + c_bhr + s3;
            const float zp = s1 + c_biz * xv + c_bhz + s4;
            const float r  = 1.0f / (1.0f + expf(-rp));
            const float z  = 1.0f / (1.0f + expf(-zp));
            const float np = s2 + c_bin * xv + r * (s5 + c_bhn);
            const float n  = tanhf(np);
            const float hnew = hv * z + (1.0f - z) * n;
            __hip_atomic_store(&hidn[(size_t)(b0 + eb) * H_DIM + ej], hnew,
                               __ATOMIC_RELAXED, __HIP_MEMORY_SCOPE_AGENT);
            float lab = (1.0f / (1.0f + expf(-(hnew * c_wo + bo)))) * xv;
            #pragma unroll
            for (int off = 8; off; off >>= 1)
                lab = fmaxf(lab, __shfl_xor(lab, off));
            if (ecol == 0) mxs[eb][etile] = lab;
        }
        __syncthreads();   // h stores drained; mxs visible; axf free

        // ---- arrive (release), then pmax + stage x(t+1) hide propagation ----
        if (tid == 0)
            __hip_atomic_fetch_add(mybar, 1u, __ATOMIC_RELEASE, __HIP_MEMORY_SCOPE_AGENT);

        if (tid < 8)
            pmax[((size_t)t * B_DIM + b0 + tid) * 32 + pair] = fmaxf(mxs[tid][0], mxs[tid][1]);

        if (t < T_DIM - 1) {
            const float* xn = x + (size_t)(t + 1) * (B_DIM * H_DIM);
            #pragma unroll
            for (int it = 0; it < 2; ++it) {
                const int fi = tid + it * 1024;
                const int r  = fi >> 8;
                const int k  = (fi & 255) * 4;
                const float4 v = *(const float4*)(xn + (size_t)(b0 + r) * H_DIM + k);
                ushort4 o; unsigned short* po = (unsigned short*)&o;
                po[0] = f2bf(v.x); po[1] = f2bf(v.y); po[2] = f2bf(v.z); po[3] = f2bf(v.w);
                const int elem = (((k >> 5) * 4 + ((k >> 3) & 3)) * 8 + r) * 8 + (k & 7);
                *(ushort4*)&axf[elem] = o;
            }
        }
    }
}

// ---------------- finalize ----------------
__global__ __launch_bounds__(256) void finalize(const float* __restrict__ pmax, int* __restrict__ out)
{
    const int i = blockIdx.x * 256 + threadIdx.x; // 0..T*B-1
    if (i >= T_DIM * B_DIM) return;
    const float4* pm = (const float4*)(pmax + (size_t)i * 32);
    float m = -3.4e38f;
    #pragma unroll
    for (int q = 0; q < 8; ++q) {
        const float4 v = pm[q];
        m = fmaxf(m, fmaxf(fmaxf(v.x, v.y), fmaxf(v.z, v.w)));
    }
    out[i] = (m >= 0.5f) ? 1 : -1;
}

extern "C" void kernel_launch(void* const* d_in, const int* in_sizes, int n_in,
                              void* d_out, int out_size, void* d_ws, size_t ws_size,
                              hipStream_t stream)
{
    const float* x    = (const float*)d_in[0];
    const float* h0   = (const float*)d_in[1];
    const float* W_ir = (const float*)d_in[2];
    const float* W_hr = (const float*)d_in[3];
    const float* W_iz = (const float*)d_in[4];
    const float* W_hz = (const float*)d_in[5];
    const float* W_in = (const float*)d_in[6];
    const float* W_hn = (const float*)d_in[7];
    const float* b_ir = (const float*)d_in[8];
    const float* b_hr = (const float*)d_in[9];
    const float* b_iz = (const float*)d_in[10];
    const float* b_hz = (const float*)d_in[11];
    const float* b_in = (const float*)d_in[12];
    const float* b_hn = (const float*)d_in[13];
    const float* W_out = (const float*)d_in[14];
    const float* b_out = (const float*)d_in[15];

    unsigned short* Wpk = (unsigned short*)d_ws;             // 6*64*32*512 bf16 = 12.58 MB
    float* hbuf = (float*)(Wpk + (size_t)6 * 64 * NKS * 512);// 2*B*H f32
    float* pmax = hbuf + (size_t)2 * B_DIM * H_DIM;          // T*B*32 f32 (4 MB)
    unsigned* barc = (unsigned*)(pmax + (size_t)T_DIM * B_DIM * 32); // 8*64 u32

    prep_pack<<<dim3(6 * 64 * NKS * 512 / 4 / 256), 256, 0, stream>>>(
        W_ir, W_iz, W_in, W_hr, W_hz, W_hn, Wpk);
    init_h<<<dim3(257), 256, 0, stream>>>(h0, hbuf, barc);

    void* args[] = {(void*)&x, (void*)&Wpk,
                    (void*)&b_ir, (void*)&b_hr, (void*)&b_iz, (void*)&b_hz,
                    (void*)&b_in, (void*)&b_hn, (void*)&W_out, (void*)&b_out,
                    (void*)&hbuf, (void*)&pmax, (void*)&barc};
    hipError_t rc = hipLaunchCooperativeKernel((const void*)gru_main, dim3(256), dim3(1024), args, 0, stream);
    (void)rc;

    finalize<<<dim3(T_DIM * B_DIM / 256), 256, 0, stream>>>(pmax, (int*)d_out);
}

// Round 14
// 9848.913 us; speedup vs baseline: 1.0414x; 1.0414x over previous
//
#include <hip/hip_runtime.h>

#define T_DIM 512
#define B_DIM 64
#define H_DIM 1024
#define NKS 32                 // MFMA K-steps (K=32 each)
#define APITCH 1032            // A-frag row pitch in ushorts (2064 B: 4-bank skew, conflict-free)

typedef __attribute__((ext_vector_type(8))) short bf16x8;
typedef __attribute__((ext_vector_type(4))) float f32x4;

// ws layout:
//   Wpk  [64 jt][32 ks][6 g][64 lane][8 e] bf16   weights in B-fragment order, tril-masked
//        (gate-innermost, jt-stride 192 KB -> no L2 set aliasing)
//   hbuf [2][B][H] f32                            hidden ping-pong (agent-scope coherent)
//   pmax [T][B][32] f32                           per-pair label maxes
//   barc [8][64] u32                              per-bgroup monotone barrier counters

__device__ __forceinline__ unsigned short f2bf(float f) {
    unsigned u = __float_as_uint(f);
    unsigned r = (u + 0x7FFFu + ((u >> 16) & 1u)) >> 16;   // RNE
    return (unsigned short)r;
}

// ---------------- prep: pack weights into MFMA B-fragment order ----------------
// elem = (((jt*32 + ks)*6 + g)*64 + lane)*8 + e
// content: B[k][j] = (k>=j ? W_g[k][j] : 0), j = jt*16 + (lane&15),
//          k = ks*32 + (lane>>4)*8 + e   (same k-map as A-frags -> layout-agnostic)
__global__ __launch_bounds__(128) void prep_pack(
    const float* __restrict__ Wir, const float* __restrict__ Wiz, const float* __restrict__ Win,
    const float* __restrict__ Whr, const float* __restrict__ Whz, const float* __restrict__ Whn,
    unsigned short* __restrict__ Wpk)
{
    const float* srcs[6] = {Wir, Wiz, Win, Whr, Whz, Whn};
    const int t    = threadIdx.x;      // 0..127
    const int jtks = blockIdx.x;       // 0..2047 = jt*32 + ks
    const int g    = blockIdx.y;       // 0..5
    const int jt   = jtks >> 5;
    const int ks   = jtks & 31;
    const int lane = t >> 1;
    const int e0   = (t & 1) * 4;
    const float* src = srcs[g];
    const int j  = jt * 16 + (lane & 15);
    const int kb = ks * 32 + (lane >> 4) * 8 + e0;
    ushort4 o;
    unsigned short* po = (unsigned short*)&o;
    #pragma unroll
    for (int i = 0; i < 4; ++i) {
        const int k = kb + i;
        const float w = (k >= j) ? src[(size_t)k * H_DIM + j] : 0.0f;
        po[i] = f2bf(w);
    }
    const size_t idx = ((((size_t)jtks) * 6 + g) * 64 + lane) * 8 + e0;
    *(ushort4*)(Wpk + idx) = o;
}

__global__ __launch_bounds__(256) void init_h(const float* __restrict__ h0,
                                              float* __restrict__ hbuf,
                                              unsigned* __restrict__ barc)
{
    if (blockIdx.x < 256) {
        const int i = blockIdx.x * 256 + threadIdx.x;
        if (i < B_DIM * H_DIM) hbuf[i] = h0[i];
    } else {
        #pragma unroll
        for (int k = 0; k < 2; ++k) barc[threadIdx.x + 256 * k] = 0u;
    }
}

// ---------------- main: 256 WGs x 1024 threads, MFMA core ----------------
// WG = (pair 0..31, bgroup 0..7 owning 8 b-rows). Tile A = 16 cols at 16*pair,
// tile B = 16 cols at 16*(63-pair). Waves 0-7 tile A (4 K-steps each), 8-15 tile B.
__global__ __launch_bounds__(1024, 4) void gru_main(
    const float* __restrict__ x,      // [T,B,H]
    const unsigned short* __restrict__ Wpk,
    const float* __restrict__ bir, const float* __restrict__ bhr,
    const float* __restrict__ biz, const float* __restrict__ bhz,
    const float* __restrict__ bin_, const float* __restrict__ bhn,
    const float* __restrict__ Wout, const float* __restrict__ bout,
    float* __restrict__ hbuf,         // [2,B,H]
    float* __restrict__ pmax,         // [T,B,32]
    unsigned* __restrict__ barc)      // [8][64]
{
    // A-frags: row-major [8 rows][128 kq8][8 e], row pitch APITCH ushorts (2064 B)
    __shared__ __align__(16) unsigned short axf[8 * APITCH];  // x A-frags, 16.1 KB
    __shared__ __align__(16) unsigned short ahf[8 * APITCH];  // h A-frags, 16.1 KB
    __shared__ __align__(16) unsigned short zblk[8];          // 16B zeros (broadcast)
    __shared__ float red[16][6][64][4];                       // per-wave acc tiles, 96 KB
    __shared__ float mxs[8][2];                               // [b][tile] label maxes

    const int tid  = threadIdx.x;
    const int lane = tid & 63;
    const int ww   = tid >> 6;        // 0..15
    const int row  = lane & 15;       // A row / D col-lane
    const int kg   = lane >> 4;       // k-group 0..3

    const int pair = blockIdx.x & 31;
    const int bg   = blockIdx.x >> 5; // 0..7 barrier group
    const int b0   = bg * 8;

    const int tile = ww >> 3;         // 0 = A, 1 = B
    const int wi   = ww & 7;          // k-slice within tile
    const int jt   = tile ? (63 - pair) : pair;
    const int ks0  = wi * 4;

    // epilogue constants (tid<256: tile = tid>>7, b = (tid>>4)&7, col = tid&15)
    const int ecol = tid & 15;
    const int eb   = (tid >> 4) & 7;
    const int ej   = ((tid >> 7) ? 16 * (63 - pair) : 16 * pair) + ecol;
    float c_bir = 0, c_bhr = 0, c_biz = 0, c_bhz = 0, c_bin = 0, c_bhn = 0, c_wo = 0, bo = 0;
    if (tid < 256) {
        c_bir = bir[ej]; c_bhr = bhr[ej]; c_biz = biz[ej]; c_bhz = bhz[ej];
        c_bin = bin_[ej]; c_bhn = bhn[ej]; c_wo = Wout[ej]; bo = bout[0];
    }

    // per-lane A-frag pointers: read 16B at row*APITCH + (ks*4+kg)*8 (ushort idx)
    const unsigned short* pax0 = (row < 8) ? &axf[row * APITCH + kg * 8] : zblk;
    const unsigned short* pah0 = (row < 8) ? &ahf[row * APITCH + kg * 8] : zblk;
    const int astride = (row < 8) ? 32 : 0;          // ushorts per ks
    // weight base: this jt, ks=0, gate 0, + lane*8; gate stride 512, ks stride 3072
    const unsigned short* pw_jt = Wpk + (size_t)jt * NKS * 3072 + lane * 8;

    unsigned* mybar = barc + bg * 64;

    if (tid < 8) zblk[tid] = 0;
    __syncthreads();

    // ---- prologue: stage x(0) as bf16 A-frags (write byte = r*2064 + (fi&255)*8) ----
    #pragma unroll
    for (int it = 0; it < 2; ++it) {
        const int fi = tid + it * 1024;           // 0..2047
        const int r  = fi >> 8;                   // b-row 0..7
        const int c  = fi & 255;                  // 16B chunk within row
        const float4 v = *(const float4*)(x + (size_t)(b0 + r) * H_DIM + c * 4);
        ushort4 o; unsigned short* po = (unsigned short*)&o;
        po[0] = f2bf(v.x); po[1] = f2bf(v.y); po[2] = f2bf(v.z); po[3] = f2bf(v.w);
        *(ushort4*)&axf[r * APITCH + c * 4] = o;
    }

    for (int t = 0; t < T_DIM; ++t) {
        const float* hid  = hbuf + (size_t)(t & 1) * (B_DIM * H_DIM);
        float*       hidn = hbuf + (size_t)((t + 1) & 1) * (B_DIM * H_DIM);
        const float* xt   = x + (size_t)t * (B_DIM * H_DIM);

        // ---- wait: h(t) visible (32 arrivals per completed step); t=0 passes ----
        if (tid == 0) {
            const unsigned tgt = 32u * (unsigned)t;
            while (__hip_atomic_load(mybar, __ATOMIC_RELAXED, __HIP_MEMORY_SCOPE_AGENT) < tgt)
                __builtin_amdgcn_s_sleep(1);
        }
        __syncthreads();

        // ---- stage h(t) as bf16 A-frags (agent-scope reads) ----
        #pragma unroll
        for (int it = 0; it < 2; ++it) {
            const int fi = tid + it * 1024;
            const int r  = fi >> 8;
            const int c  = fi & 255;
            const float* s4 = hid + (size_t)(b0 + r) * H_DIM + c * 4;
            float4 v;
            v.x = __hip_atomic_load(s4 + 0, __ATOMIC_RELAXED, __HIP_MEMORY_SCOPE_AGENT);
            v.y = __hip_atomic_load(s4 + 1, __ATOMIC_RELAXED, __HIP_MEMORY_SCOPE_AGENT);
            v.z = __hip_atomic_load(s4 + 2, __ATOMIC_RELAXED, __HIP_MEMORY_SCOPE_AGENT);
            v.w = __hip_atomic_load(s4 + 3, __ATOMIC_RELAXED, __HIP_MEMORY_SCOPE_AGENT);
            ushort4 o; unsigned short* po = (unsigned short*)&o;
            po[0] = f2bf(v.x); po[1] = f2bf(v.y); po[2] = f2bf(v.z); po[3] = f2bf(v.w);
            *(ushort4*)&ahf[r * APITCH + c * 4] = o;
        }
        __syncthreads();

        // ---- MFMA phase: 4 ksteps x 6 gates, fp32 accumulate ----
        f32x4 acc0 = 0.0f, acc1 = 0.0f, acc2 = 0.0f;   // x-gates: ir, iz, in
        f32x4 acc3 = 0.0f, acc4 = 0.0f, acc5 = 0.0f;   // h-gates: hr, hz, hn
        #pragma unroll
        for (int q = 0; q < 4; ++q) {
            const int ks = ks0 + q;
            const bf16x8 ax = *(const bf16x8*)(pax0 + ks * astride);
            const bf16x8 ah = *(const bf16x8*)(pah0 + ks * astride);
            const unsigned short* pw = pw_jt + (size_t)ks * 3072;
            const bf16x8 w0 = *(const bf16x8*)(pw);
            const bf16x8 w1 = *(const bf16x8*)(pw + 512);
            const bf16x8 w2 = *(const bf16x8*)(pw + 1024);
            const bf16x8 w3 = *(const bf16x8*)(pw + 1536);
            const bf16x8 w4 = *(const bf16x8*)(pw + 2048);
            const bf16x8 w5 = *(const bf16x8*)(pw + 2560);
            acc0 = __builtin_amdgcn_mfma_f32_16x16x32_bf16(ax, w0, acc0, 0, 0, 0);
            acc1 = __builtin_amdgcn_mfma_f32_16x16x32_bf16(ax, w1, acc1, 0, 0, 0);
            acc2 = __builtin_amdgcn_mfma_f32_16x16x32_bf16(ax, w2, acc2, 0, 0, 0);
            acc3 = __builtin_amdgcn_mfma_f32_16x16x32_bf16(ah, w3, acc3, 0, 0, 0);
            acc4 = __builtin_amdgcn_mfma_f32_16x16x32_bf16(ah, w4, acc4, 0, 0, 0);
            acc5 = __builtin_amdgcn_mfma_f32_16x16x32_bf16(ah, w5, acc5, 0, 0, 0);
        }

        // ---- write acc tiles to LDS ----
        *(f32x4*)&red[ww][0][lane][0] = acc0;
        *(f32x4*)&red[ww][1][lane][0] = acc1;
        *(f32x4*)&red[ww][2][lane][0] = acc2;
        *(f32x4*)&red[ww][3][lane][0] = acc3;
        *(f32x4*)&red[ww][4][lane][0] = acc4;
        *(f32x4*)&red[ww][5][lane][0] = acc5;
        __syncthreads();

        // ---- epilogue: 256 threads = (tile 2) x (b 8) x (col 16) ----
        if (tid < 256) {
            const int etile = tid >> 7;
            const int wbase = etile * 8;
            const int lp = ((eb >> 2) << 4) | ecol;   // D lane': row-group | col
            const int rr = eb & 3;                    // D reg index
            float s0 = 0, s1 = 0, s2 = 0, s3 = 0, s4 = 0, s5 = 0;
            #pragma unroll
            for (int wv = 0; wv < 8; ++wv) {
                s0 += red[wbase + wv][0][lp][rr];
                s1 += red[wbase + wv][1][lp][rr];
                s2 += red[wbase + wv][2][lp][rr];
                s3 += red[wbase + wv][3][lp][rr];
                s4 += red[wbase + wv][4][lp][rr];
                s5 += red[wbase + wv][5][lp][rr];
            }
            const float xv = xt[(size_t)(b0 + eb) * H_DIM + ej];
            const float hv = __hip_atomic_load(&hid[(size_t)(b0 + eb) * H_DIM + ej],
                                               __ATOMIC_RELAXED, __HIP_MEMORY_SCOPE_AGENT);
            const float rp = s0 + c_bir * xv + c_bhr + s3;
            const float zp = s1 + c_biz * xv + c_bhz + s4;
            const float r  = 1.0f / (1.0f + expf(-rp));
            const float z  = 1.0f / (1.0f + expf(-zp));
            const float np = s2 + c_bin * xv + r * (s5 + c_bhn);
            const float n  = tanhf(np);
            const float hnew = hv * z + (1.0f - z) * n;
            __hip_atomic_store(&hidn[(size_t)(b0 + eb) * H_DIM + ej], hnew,
                               __ATOMIC_RELAXED, __HIP_MEMORY_SCOPE_AGENT);
            float lab = (1.0f / (1.0f + expf(-(hnew * c_wo + bo)))) * xv;
            #pragma unroll
            for (int off = 8; off; off >>= 1)
                lab = fmaxf(lab, __shfl_xor(lab, off));
            if (ecol == 0) mxs[eb][etile] = lab;
        }
        __syncthreads();   // h stores drained; mxs visible; axf free

        // ---- arrive (release), then pmax + stage x(t+1) hide propagation ----
        if (tid == 0)
            __hip_atomic_fetch_add(mybar, 1u, __ATOMIC_RELEASE, __HIP_MEMORY_SCOPE_AGENT);

        if (tid < 8)
            pmax[((size_t)t * B_DIM + b0 + tid) * 32 + pair] = fmaxf(mxs[tid][0], mxs[tid][1]);

        if (t < T_DIM - 1) {
            const float* xn = x + (size_t)(t + 1) * (B_DIM * H_DIM);
            #pragma unroll
            for (int it = 0; it < 2; ++it) {
                const int fi = tid + it * 1024;
                const int r  = fi >> 8;
                const int c  = fi & 255;
                const float4 v = *(const float4*)(xn + (size_t)(b0 + r) * H_DIM + c * 4);
                ushort4 o; unsigned short* po = (unsigned short*)&o;
                po[0] = f2bf(v.x); po[1] = f2bf(v.y); po[2] = f2bf(v.z); po[3] = f2bf(v.w);
                *(ushort4*)&axf[r * APITCH + c * 4] = o;
            }
        }
    }
}

// ---------------- finalize ----------------
__global__ __launch_bounds__(256) void finalize(const float* __restrict__ pmax, int* __restrict__ out)
{
    const int i = blockIdx.x * 256 + threadIdx.x; // 0..T*B-1
    if (i >= T_DIM * B_DIM) return;
    const float4* pm = (const float4*)(pmax + (size_t)i * 32);
    float m = -3.4e38f;
    #pragma unroll
    for (int q = 0; q < 8; ++q) {
        const float4 v = pm[q];
        m = fmaxf(m, fmaxf(fmaxf(v.x, v.y), fmaxf(v.z, v.w)));
    }
    out[i] = (m >= 0.5f) ? 1 : -1;
}

extern "C" void kernel_launch(void* const* d_in, const int* in_sizes, int n_in,
                              void* d_out, int out_size, void* d_ws, size_t ws_size,
                              hipStream_t stream)
{
    const float* x    = (const float*)d_in[0];
    const float* h0   = (const float*)d_in[1];
    const float* W_ir = (const float*)d_in[2];
    const float* W_hr = (const float*)d_in[3];
    const float* W_iz = (const float*)d_in[4];
    const float* W_hz = (const float*)d_in[5];
    const float* W_in = (const float*)d_in[6];
    const float* W_hn = (const float*)d_in[7];
    const float* b_ir = (const float*)d_in[8];
    const float* b_hr = (const float*)d_in[9];
    const float* b_iz = (const float*)d_in[10];
    const float* b_hz = (const float*)d_in[11];
    const float* b_in = (const float*)d_in[12];
    const float* b_hn = (const float*)d_in[13];
    const float* W_out = (const float*)d_in[14];
    const float* b_out = (const float*)d_in[15];

    unsigned short* Wpk = (unsigned short*)d_ws;             // 64*32*6*512 bf16 = 12.58 MB
    float* hbuf = (float*)(Wpk + (size_t)64 * NKS * 6 * 512);// 2*B*H f32
    float* pmax = hbuf + (size_t)2 * B_DIM * H_DIM;          // T*B*32 f32 (4 MB)
    unsigned* barc = (unsigned*)(pmax + (size_t)T_DIM * B_DIM * 32); // 8*64 u32

    prep_pack<<<dim3(2048, 6), 128, 0, stream>>>(W_ir, W_iz, W_in, W_hr, W_hz, W_hn, Wpk);
    init_h<<<dim3(257), 256, 0, stream>>>(h0, hbuf, barc);

    void* args[] = {(void*)&x, (void*)&Wpk,
                    (void*)&b_ir, (void*)&b_hr, (void*)&b_iz, (void*)&b_hz,
                    (void*)&b_in, (void*)&b_hn, (void*)&W_out, (void*)&b_out,
                    (void*)&hbuf, (void*)&pmax, (void*)&barc};
    hipError_t rc = hipLaunchCooperativeKernel((const void*)gru_main, dim3(256), dim3(1024), args, 0, stream);
    (void)rc;

    finalize<<<dim3(T_DIM * B_DIM / 256), 256, 0, stream>>>(pmax, (int*)d_out);
}

// Round 15
// 6086.681 us; speedup vs baseline: 1.6852x; 1.6181x over previous
//
#include <hip/hip_runtime.h>

#define T_DIM 512
#define B_DIM 64
#define H_DIM 1024
#define KSLOT 33               // padded ks slots per jt (32 real): 198KB jt stride, set-decorrelated
#define APITCH 1032            // A-frag row pitch in ushorts (2064B)
#define AHEAD 6                // max run-ahead (ring depth 8)

typedef __attribute__((ext_vector_type(8))) short bf16x8;
typedef __attribute__((ext_vector_type(4))) float f32x4;

// ws layout:
//   Wpk   [64 jt][33 ks][6 g][64 lane][8 e] bf16  B-fragments, tril-masked (slot 32 unused)
//   hring [8][B][H] bf16                          h state ring (agent-coherent)
//   pmax  [T][B][64] f32                          per-block label maxes
//   prog  [4 bg][64 jt][16] u32                   progress flags (64B lines)

__device__ __forceinline__ unsigned short f2bf(float f) {
    unsigned u = __float_as_uint(f);
    unsigned r = (u + 0x7FFFu + ((u >> 16) & 1u)) >> 16;   // RNE
    return (unsigned short)r;
}
__device__ __forceinline__ unsigned pack2(float a, float b) {
    return (unsigned)f2bf(a) | ((unsigned)f2bf(b) << 16);
}

// ---------------- prep: pack weights into per-block MFMA B-fragment order ----------------
__global__ __launch_bounds__(128) void prep_pack(
    const float* __restrict__ Wir, const float* __restrict__ Wiz, const float* __restrict__ Win,
    const float* __restrict__ Whr, const float* __restrict__ Whz, const float* __restrict__ Whn,
    unsigned short* __restrict__ Wpk)
{
    const float* srcs[6] = {Wir, Wiz, Win, Whr, Whz, Whn};
    const int t    = threadIdx.x;
    const int jtks = blockIdx.x;       // jt*32 + ks
    const int g    = blockIdx.y;
    const int jt   = jtks >> 5, ks = jtks & 31;
    const int lane = t >> 1, e0 = (t & 1) * 4;
    const float* src = srcs[g];
    const int j  = jt * 16 + (lane & 15);
    const int kb = ks * 32 + (lane >> 4) * 8 + e0;
    ushort4 o; unsigned short* po = (unsigned short*)&o;
    #pragma unroll
    for (int i = 0; i < 4; ++i) {
        const int k = kb + i;
        const float w = (k >= j) ? src[(size_t)k * H_DIM + j] : 0.0f;
        po[i] = f2bf(w);
    }
    const size_t idx = ((((size_t)jt * KSLOT + ks) * 6 + g) * 64 + lane) * 8 + e0;
    *(ushort4*)(Wpk + idx) = o;
}

// ---------------- init: h0 -> ring slot 0 (bf16); zero progress flags ----------------
__global__ __launch_bounds__(256) void init_h(const float* __restrict__ h0,
                                              unsigned short* __restrict__ hring,
                                              unsigned* __restrict__ prog)
{
    if (blockIdx.x < 256) {
        const int i = blockIdx.x * 256 + threadIdx.x;   // B*H = 65536
        hring[i] = f2bf(h0[i]);
    } else {
        #pragma unroll
        for (int k = 0; k < 16; ++k) prog[threadIdx.x + 256 * k] = 0u;  // 4*64*16
    }
}

// ---------------- main: 256 WGs x 512 threads, triangular dataflow ----------------
// WG = (jt 0..63 column block, bg 0..3 owning 16 b-rows). Block jt at iter t needs
// state t of blocks kt >= jt (same bg) only -> per-block flags, no global barrier.
// Higher blocks run ahead (<= AHEAD); in steady state polls pass on first try.
__global__ __launch_bounds__(512) void gru_main(
    const float* __restrict__ x,      // [T,B,H]
    const unsigned short* __restrict__ Wpk,
    const float* __restrict__ bir, const float* __restrict__ bhr,
    const float* __restrict__ biz, const float* __restrict__ bhz,
    const float* __restrict__ bin_, const float* __restrict__ bhn,
    const float* __restrict__ Wout, const float* __restrict__ bout,
    const float* __restrict__ h0,
    unsigned short* __restrict__ hring,  // [8][B][H] bf16
    float* __restrict__ pmax,            // [T,B,64]
    unsigned* __restrict__ prog)         // [4][64][16]
{
    __shared__ __align__(16) unsigned short axf[16 * APITCH];  // x A-frags (33 KB)
    __shared__ __align__(16) unsigned short ahf[16 * APITCH];  // h A-frags (33 KB)
    __shared__ float red[8][6][64][4];                         // 48 KB
    __shared__ float hown[16][17];                             // own-block h, f32 exact
    __shared__ unsigned short hb[16][16];                      // own-block h, bf16

    const int tid  = threadIdx.x;
    const int lane = tid & 63;
    const int wv   = tid >> 6;        // 0..7

    const int jt = blockIdx.x & 63;   // XCD = blockIdx%8 = jt%8 -> weight slices XCD-pinned
    const int bg = blockIdx.x >> 6;   // 0..3
    const int b0 = bg * 16;

    const int ksb   = jt >> 1;
    const int kcol0 = ksb * 32;
    const int CHN   = (H_DIM - kcol0) >> 3;   // 16B chunks per staged row
    const int cnt   = 32 - ksb;
    const int kpw   = (cnt + 7) >> 3;
    const int ks_s  = ksb + wv * kpw;
    const int ks_e  = (ks_s + kpw < 32) ? (ks_s + kpw) : 32;

    const int row = lane & 15;
    const int kg  = lane >> 4;
    const unsigned short* pax = &axf[row * APITCH + kg * 8];
    const unsigned short* pah = &ahf[row * APITCH + kg * 8];
    const unsigned short* pw0 = Wpk + (size_t)jt * KSLOT * 3072 + lane * 8;

    // epilogue constants (tid<256: eb = tid>>4, ecol = tid&15)
    const int ecol = tid & 15;
    const int eb   = tid >> 4;
    const int ej   = 16 * jt + ecol;
    float c_bir = 0, c_bhr = 0, c_biz = 0, c_bhz = 0, c_bin = 0, c_bhn = 0, c_wo = 0, bo = 0;
    if (tid < 256) {
        c_bir = bir[ej]; c_bhr = bhr[ej]; c_biz = biz[ej]; c_bhz = bhz[ej];
        c_bin = bin_[ej]; c_bhn = bhn[ej]; c_wo = Wout[ej]; bo = bout[0];
    }

    unsigned* myflag = prog + ((bg << 6) + jt) * 16;
    unsigned* pollp  = prog + ((bg << 6) + lane) * 16;

    // prologue: own-block h0 (f32) + stage x(0)
    if (tid < 256) hown[eb][ecol] = h0[(size_t)(b0 + eb) * H_DIM + ej];
    #pragma unroll
    for (int rr = 0; rr < 2; ++rr) {
        const int r = 2 * wv + rr;
        const float* src = x + (size_t)(b0 + r) * H_DIM + kcol0;
        #pragma unroll
        for (int s = 0; s < 2; ++s) {
            const int c8 = lane + (s << 6);
            if (c8 < CHN) {
                const float4 v0 = *(const float4*)(src + c8 * 8);
                const float4 v1 = *(const float4*)(src + c8 * 8 + 4);
                uint4 o = make_uint4(pack2(v0.x, v0.y), pack2(v0.z, v0.w),
                                     pack2(v1.x, v1.y), pack2(v1.z, v1.w));
                *(uint4*)&axf[r * APITCH + c8 * 8] = o;
            }
        }
    }

    for (int t = 0; t < T_DIM; ++t) {
        const int slot_r = t & 7, slot_w = (t + 1) & 7;

        // ---- poll: inputs (kt>=jt at state t) + ring backpressure (kt<=jt at t-AHEAD) ----
        if (tid < 64) {
            const int kt = lane;
            int thr = -1000000;
            if (kt >= jt) thr = t;
            if (kt <= jt && t - AHEAD > thr) thr = t - AHEAD;
            for (;;) {
                const unsigned v = __hip_atomic_load(pollp, __ATOMIC_RELAXED,
                                                     __HIP_MEMORY_SCOPE_AGENT);
                if (__all((int)v >= thr)) break;
                __builtin_amdgcn_s_sleep(2);
            }
        }
        __syncthreads();

        // ---- stage h(t) rows b0..b0+15, cols >= kcol0, from bf16 ring ----
        #pragma unroll
        for (int rr = 0; rr < 2; ++rr) {
            const int r = 2 * wv + rr;
            const unsigned* src = (const unsigned*)(hring +
                ((size_t)slot_r * B_DIM + b0 + r) * H_DIM + kcol0);
            #pragma unroll
            for (int s = 0; s < 2; ++s) {
                const int c8 = lane + (s << 6);
                if (c8 < CHN) {
                    const unsigned* p4 = src + c8 * 4;
                    uint4 o;
                    o.x = __hip_atomic_load(p4 + 0, __ATOMIC_RELAXED, __HIP_MEMORY_SCOPE_AGENT);
                    o.y = __hip_atomic_load(p4 + 1, __ATOMIC_RELAXED, __HIP_MEMORY_SCOPE_AGENT);
                    o.z = __hip_atomic_load(p4 + 2, __ATOMIC_RELAXED, __HIP_MEMORY_SCOPE_AGENT);
                    o.w = __hip_atomic_load(p4 + 3, __ATOMIC_RELAXED, __HIP_MEMORY_SCOPE_AGENT);
                    *(uint4*)&ahf[r * APITCH + c8 * 8] = o;
                }
            }
        }
        __syncthreads();
        // own-block columns from exact local copy (also covers un-polled jt-1 parity: masked)
        if (tid < 256) {
            const int kk = ((jt & 1) << 4) + ecol;
            ahf[eb * APITCH + kk] = f2bf(hown[eb][ecol]);
        }
        __syncthreads();

        // ---- MFMA: this wave's ks slice, 6 gates ----
        f32x4 a0 = 0.f, a1 = 0.f, a2 = 0.f, a3 = 0.f, a4 = 0.f, a5 = 0.f;
        for (int ks = ks_s; ks < ks_e; ++ks) {
            const int off = (ks - ksb) * 32;
            const bf16x8 ax = *(const bf16x8*)(pax + off);
            const bf16x8 ah = *(const bf16x8*)(pah + off);
            const unsigned short* pw = pw0 + (size_t)ks * 3072;
            const bf16x8 w0 = *(const bf16x8*)(pw);
            const bf16x8 w1 = *(const bf16x8*)(pw + 512);
            const bf16x8 w2 = *(const bf16x8*)(pw + 1024);
            const bf16x8 w3 = *(const bf16x8*)(pw + 1536);
            const bf16x8 w4 = *(const bf16x8*)(pw + 2048);
            const bf16x8 w5 = *(const bf16x8*)(pw + 2560);
            a0 = __builtin_amdgcn_mfma_f32_16x16x32_bf16(ax, w0, a0, 0, 0, 0);
            a1 = __builtin_amdgcn_mfma_f32_16x16x32_bf16(ax, w1, a1, 0, 0, 0);
            a2 = __builtin_amdgcn_mfma_f32_16x16x32_bf16(ax, w2, a2, 0, 0, 0);
            a3 = __builtin_amdgcn_mfma_f32_16x16x32_bf16(ah, w3, a3, 0, 0, 0);
            a4 = __builtin_amdgcn_mfma_f32_16x16x32_bf16(ah, w4, a4, 0, 0, 0);
            a5 = __builtin_amdgcn_mfma_f32_16x16x32_bf16(ah, w5, a5, 0, 0, 0);
        }
        *(f32x4*)&red[wv][0][lane][0] = a0;
        *(f32x4*)&red[wv][1][lane][0] = a1;
        *(f32x4*)&red[wv][2][lane][0] = a2;
        *(f32x4*)&red[wv][3][lane][0] = a3;
        *(f32x4*)&red[wv][4][lane][0] = a4;
        *(f32x4*)&red[wv][5][lane][0] = a5;
        __syncthreads();

        // ---- epilogue: 256 threads = (b 16) x (col 16) ----
        if (tid < 256) {
            const int lp = ((eb >> 2) << 4) | ecol;   // D: col=lane&15, row=(lane>>4)*4+reg
            const int rg = eb & 3;
            float s0 = 0, s1 = 0, s2 = 0, s3 = 0, s4 = 0, s5 = 0;
            #pragma unroll
            for (int w2i = 0; w2i < 8; ++w2i) {
                s0 += red[w2i][0][lp][rg]; s1 += red[w2i][1][lp][rg];
                s2 += red[w2i][2][lp][rg]; s3 += red[w2i][3][lp][rg];
                s4 += red[w2i][4][lp][rg]; s5 += red[w2i][5][lp][rg];
            }
            const float xv = x[(size_t)t * B_DIM * H_DIM + (size_t)(b0 + eb) * H_DIM + ej];
            const float hv = hown[eb][ecol];
            const float rp = s0 + c_bir * xv + c_bhr + s3;
            const float zp = s1 + c_biz * xv + c_bhz + s4;
            const float r  = 1.0f / (1.0f + expf(-rp));
            const float z  = 1.0f / (1.0f + expf(-zp));
            const float np = s2 + c_bin * xv + r * (s5 + c_bhn);
            const float n  = tanhf(np);
            const float hnew = hv * z + (1.0f - z) * n;
            hown[eb][ecol] = hnew;
            hb[eb][ecol] = f2bf(hnew);
            float lab = (1.0f / (1.0f + expf(-(hnew * c_wo + bo)))) * xv;
            #pragma unroll
            for (int off = 8; off; off >>= 1)
                lab = fmaxf(lab, __shfl_xor(lab, off));
            if (ecol == 0) pmax[((size_t)t * B_DIM + b0 + eb) * 64 + jt] = lab;
        }
        __syncthreads();

        // ---- publish own 16 columns (bf16, u32-packed) to ring slot t+1 ----
        if (tid < 128) {
            const int b = tid >> 3, cq = tid & 7;
            const unsigned val = (unsigned)hb[b][2 * cq] | ((unsigned)hb[b][2 * cq + 1] << 16);
            unsigned* dst = (unsigned*)(hring + ((size_t)slot_w * B_DIM + b0 + b) * H_DIM
                                        + 16 * jt) + cq;
            __hip_atomic_store(dst, val, __ATOMIC_RELAXED, __HIP_MEMORY_SCOPE_AGENT);
        }
        __syncthreads();   // ring stores drained (vmcnt) before flag
        if (tid == 0)
            __hip_atomic_store(myflag, (unsigned)(t + 1),
                               __ATOMIC_RELEASE, __HIP_MEMORY_SCOPE_AGENT);

        // ---- tail: stage x(t+1) (independent; hides flag propagation) ----
        if (t < T_DIM - 1) {
            const float* xs = x + (size_t)(t + 1) * B_DIM * H_DIM;
            #pragma unroll
            for (int rr = 0; rr < 2; ++rr) {
                const int r = 2 * wv + rr;
                const float* src = xs + (size_t)(b0 + r) * H_DIM + kcol0;
                #pragma unroll
                for (int s = 0; s < 2; ++s) {
                    const int c8 = lane + (s << 6);
                    if (c8 < CHN) {
                        const float4 v0 = *(const float4*)(src + c8 * 8);
                        const float4 v1 = *(const float4*)(src + c8 * 8 + 4);
                        uint4 o = make_uint4(pack2(v0.x, v0.y), pack2(v0.z, v0.w),
                                             pack2(v1.x, v1.y), pack2(v1.z, v1.w));
                        *(uint4*)&axf[r * APITCH + c8 * 8] = o;
                    }
                }
            }
        }
    }
}

// ---------------- finalize: max over 64 block-maxes, threshold, emit int32 ----------------
__global__ __launch_bounds__(256) void finalize(const float* __restrict__ pmax, int* __restrict__ out)
{
    const int i = blockIdx.x * 256 + threadIdx.x; // 0..T*B-1
    if (i >= T_DIM * B_DIM) return;
    const float4* pm = (const float4*)(pmax + (size_t)i * 64);
    float m = -3.4e38f;
    #pragma unroll
    for (int q = 0; q < 16; ++q) {
        const float4 v = pm[q];
        m = fmaxf(m, fmaxf(fmaxf(v.x, v.y), fmaxf(v.z, v.w)));
    }
    out[i] = (m >= 0.5f) ? 1 : -1;
}

extern "C" void kernel_launch(void* const* d_in, const int* in_sizes, int n_in,
                              void* d_out, int out_size, void* d_ws, size_t ws_size,
                              hipStream_t stream)
{
    const float* x    = (const float*)d_in[0];
    const float* h0   = (const float*)d_in[1];
    const float* W_ir = (const float*)d_in[2];
    const float* W_hr = (const float*)d_in[3];
    const float* W_iz = (const float*)d_in[4];
    const float* W_hz = (const float*)d_in[5];
    const float* W_in = (const float*)d_in[6];
    const float* W_hn = (const float*)d_in[7];
    const float* b_ir = (const float*)d_in[8];
    const float* b_hr = (const float*)d_in[9];
    const float* b_iz = (const float*)d_in[10];
    const float* b_hz = (const float*)d_in[11];
    const float* b_in = (const float*)d_in[12];
    const float* b_hn = (const float*)d_in[13];
    const float* W_out = (const float*)d_in[14];
    const float* b_out = (const float*)d_in[15];

    unsigned short* Wpk   = (unsigned short*)d_ws;                    // 64*33*3072 ushorts (~13 MB)
    unsigned short* hring = Wpk + (size_t)64 * KSLOT * 3072;          // 8*B*H ushorts (1 MB)
    float* pmax = (float*)(hring + (size_t)8 * B_DIM * H_DIM);        // T*B*64 f32 (8 MB)
    unsigned* prog = (unsigned*)(pmax + (size_t)T_DIM * B_DIM * 64);  // 4*64*16 u32

    prep_pack<<<dim3(64 * 32, 6), 128, 0, stream>>>(W_ir, W_iz, W_in, W_hr, W_hz, W_hn, Wpk);
    init_h<<<dim3(257), 256, 0, stream>>>(h0, hring, prog);

    void* args[] = {(void*)&x, (void*)&Wpk,
                    (void*)&b_ir, (void*)&b_hr, (void*)&b_iz, (void*)&b_hz,
                    (void*)&b_in, (void*)&b_hn, (void*)&W_out, (void*)&b_out,
                    (void*)&h0, (void*)&hring, (void*)&pmax, (void*)&prog};
    hipError_t rc = hipLaunchCooperativeKernel((const void*)gru_main, dim3(256), dim3(512),
                                               args, 0, stream);
    (void)rc;

    finalize<<<dim3(T_DIM * B_DIM / 256), 256, 0, stream>>>(pmax, (int*)d_out);
}